// Round 6
// baseline (171.085 us; speedup 1.0000x reference)
//
#include <hip/hip_runtime.h>

typedef unsigned short u16;
typedef float f32x4 __attribute__((ext_vector_type(4)));
typedef short bf16x8 __attribute__((ext_vector_type(8)));

#define MFMA16(a, b, c) __builtin_amdgcn_mfma_f32_16x16x32_bf16((a), (b), (c), 0, 0, 0)
// XOR swizzle in 16B (8-short) units within a 64-short row
#define SWZ8(row, off) ((off) ^ (((row) & 7) << 3))

#define CFENCE() asm volatile("" ::: "memory")
#define BARRIER() do { CFENCE(); __builtin_amdgcn_s_barrier(); CFENCE(); } while (0)
#define VMW(n) asm volatile("s_waitcnt vmcnt(" #n ")" ::: "memory")

// round-to-nearest-even f32 -> bf16 (software; proven rounds 0-2)
static __device__ __forceinline__ u16 f2bf(float f) {
  union { float f; unsigned u; } c; c.f = f;
  unsigned r = c.u + 0x7fffu + ((c.u >> 16) & 1u);
  return (u16)(r >> 16);
}

// hardware 2^x (v_exp_f32 IS exp2)
static __device__ __forceinline__ float exp2_hw(float x) {
  float r;
  asm("v_exp_f32 %0, %1" : "=v"(r) : "v"(x));
  return r;
}

// packed f32x2 -> bf16x2 (used ONLY for P, the tolerance-insensitive site)
static __device__ __forceinline__ unsigned cvtpk(float lo, float hi) {
  unsigned r;
  asm("v_cvt_pk_bf16_f32 %0, %1, %2" : "=v"(r) : "v"(lo), "v"(hi));
  return r;
}

static __device__ __forceinline__ void llds16(u16* l, const u16* g) {
  __builtin_amdgcn_global_load_lds((const __attribute__((address_space(1))) void*)g,
                                   (__attribute__((address_space(3))) void*)l, 16, 0, 0);
}

// ---------------- prep: transpose weights to bf16 [N][K] ----------------
__global__ __launch_bounds__(256) void prep_weights(
    const float* __restrict__ w_qkv, const float* __restrict__ w_out,
    u16* __restrict__ wqkvT, u16* __restrict__ woutT) {
  int idx = blockIdx.x * 256 + threadIdx.x;
  if (idx < 1536 * 512) {
    int n = idx >> 9, k = idx & 511;
    wqkvT[idx] = f2bf(w_qkv[k * 1536 + n]);
  } else {
    int j = idx - 1536 * 512;
    int n = j >> 9, k = j & 511;
    woutT[j] = f2bf(w_out[k * 512 + n]);
  }
}

// ---------------- LayerNorm -> bf16 (one wave per row; f2bf rounding) ----------------
__global__ __launch_bounds__(256) void ln_kernel(
    const float* __restrict__ x, const float* __restrict__ g,
    const float* __restrict__ be, u16* __restrict__ xn) {
  int row = blockIdx.x * 4 + (threadIdx.x >> 6);
  int lane = threadIdx.x & 63;
  const float4* xr = (const float4*)(x + (size_t)row * 512) + lane * 2;
  float4 v0 = xr[0], v1 = xr[1];
  float s = v0.x + v0.y + v0.z + v0.w + v1.x + v1.y + v1.z + v1.w;
  float ss = v0.x * v0.x + v0.y * v0.y + v0.z * v0.z + v0.w * v0.w +
             v1.x * v1.x + v1.y * v1.y + v1.z * v1.z + v1.w * v1.w;
#pragma unroll
  for (int msk = 32; msk >= 1; msk >>= 1) {
    s += __shfl_xor(s, msk, 64);
    ss += __shfl_xor(ss, msk, 64);
  }
  float mu = s * (1.f / 512.f);
  float var = ss * (1.f / 512.f) - mu * mu;
  float rs = rsqrtf(var + 1e-5f);
  const float4* gp = (const float4*)g + lane * 2;
  const float4* bp = (const float4*)be + lane * 2;
  float4 g0 = gp[0], g1 = gp[1], b0 = bp[0], b1 = bp[1];
  union { u16 h[8]; uint4 q; } o;
  o.h[0] = f2bf((v0.x - mu) * rs * g0.x + b0.x);
  o.h[1] = f2bf((v0.y - mu) * rs * g0.y + b0.y);
  o.h[2] = f2bf((v0.z - mu) * rs * g0.z + b0.z);
  o.h[3] = f2bf((v0.w - mu) * rs * g0.w + b0.w);
  o.h[4] = f2bf((v1.x - mu) * rs * g1.x + b1.x);
  o.h[5] = f2bf((v1.y - mu) * rs * g1.y + b1.y);
  o.h[6] = f2bf((v1.z - mu) * rs * g1.z + b1.z);
  o.h[7] = f2bf((v1.w - mu) * rs * g1.w + b1.w);
  *(uint4*)&xn[(size_t)row * 512 + lane * 8] = o.q;
}

// ---------------- QKV GEMM: [8192,512] x [512,1536], scatter q/k/vT ----------------
// q pre-scaled by 0.125 * log2(e) so attention softmax runs in exp2 domain.
__global__ __launch_bounds__(256) void gemm_qkv(
    const u16* __restrict__ A, const u16* __restrict__ BT,
    u16* __restrict__ qb, u16* __restrict__ kb, u16* __restrict__ vtb) {
  __shared__ u16 lsA[128 * 64], lsB[128 * 64];
  int m0 = blockIdx.x * 128, n0 = blockIdx.y * 128;
  int tid = threadIdx.x;
  int lane = tid & 63, wave = tid >> 6;
  int wm = (wave >> 1) * 64, wn = (wave & 1) * 64;
  int lr = lane & 15, lq = lane >> 4;
  f32x4 acc[4][4] = {};
  for (int kt = 0; kt < 8; ++kt) {
#pragma unroll
    for (int c = 0; c < 4; ++c) {
      int ci = c * 256 + tid;
      int row = ci >> 3, colb = ci & 7;
      int goff = kt * 64 + ((colb * 8) ^ ((row & 7) * 8));
      llds16(&lsA[ci * 8], &A[(size_t)(m0 + row) * 512 + goff]);
      llds16(&lsB[ci * 8], &BT[(size_t)(n0 + row) * 512 + goff]);
    }
    __syncthreads();
#pragma unroll
    for (int ks = 0; ks < 2; ++ks) {
      bf16x8 af[4], bfr[4];
#pragma unroll
      for (int i = 0; i < 4; ++i) {
        int ra = wm + i * 16 + lr;
        af[i] = *(const bf16x8*)&lsA[ra * 64 + SWZ8(ra, ks * 32 + lq * 8)];
        int rb = wn + i * 16 + lr;
        bfr[i] = *(const bf16x8*)&lsB[rb * 64 + SWZ8(rb, ks * 32 + lq * 8)];
      }
#pragma unroll
      for (int i = 0; i < 4; ++i)
#pragma unroll
        for (int j = 0; j < 4; ++j)
          acc[i][j] = MFMA16(af[i], bfr[j], acc[i][j]);
    }
    __syncthreads();
  }
  // epilogue: n<512 -> q (scaled), <1024 -> k, else v transposed [B,H,D,T]
#pragma unroll
  for (int j = 0; j < 4; ++j) {
    int gn = n0 + wn + j * 16 + lr;
    int sec = gn >> 9;
    int h = (gn >> 6) & 7;
    int d = gn & 63;
#pragma unroll
    for (int i = 0; i < 4; ++i) {
      int gm = m0 + wm + i * 16 + lq * 4;
      int b = gm >> 11, t0 = gm & 2047;
      int bh = b * 8 + h;
      if (sec == 0) {
#pragma unroll
        for (int r = 0; r < 4; ++r)
          qb[((size_t)bh * 2048 + t0 + r) * 64 + d] = f2bf(acc[i][j][r] * 0.180336880f);
      } else if (sec == 1) {
#pragma unroll
        for (int r = 0; r < 4; ++r)
          kb[((size_t)bh * 2048 + t0 + r) * 64 + d] = f2bf(acc[i][j][r]);
      } else {
        ushort4 pk;
        pk.x = f2bf(acc[i][j][0]);
        pk.y = f2bf(acc[i][j][1]);
        pk.z = f2bf(acc[i][j][2]);
        pk.w = f2bf(acc[i][j][3]);
        *(ushort4*)&vtb[((size_t)bh * 64 + d) * 2048 + t0] = pk;
      }
    }
  }
}

// ---------------- frame-causal flash attention (pair-balanced) ----------------
// Each block handles TWO q-frames of one bh: qfA = 31-pair (heavy) and
// qfB = pair, sharing one staged pass over kf = 0..qfA (B updated while
// kf <= qfB; K/V ds_reads shared on dual iterations). Every block does
// exactly 33 frame-tile softmaxes -> perfectly balanced makespan.
// Swapped QK^T -> lane-local softmax (q = lane&15); P via proven LDS path.
__global__ __launch_bounds__(256) void attn_kernel(
    const u16* __restrict__ qb, const u16* __restrict__ kb,
    const u16* __restrict__ vtb, u16* __restrict__ ao) {
  int blk = blockIdx.x;          // 512 blocks
  int xcd = blk & 7;
  int seq = blk >> 3;            // 0..63
  int bh = xcd * 4 + (seq & 3);  // 4 bh per XCD -> L2-resident K/V
  int pair = seq >> 2;           // 0..15
  int qfA = 31 - pair, qfB = pair;
  int tid = threadIdx.x, lane = tid & 63, wave = tid >> 6;
  int lr = lane & 15, lq = lane >> 4;
  __shared__ u16 lsK[2][64 * 64], lsV[2][64 * 64];
  __shared__ u16 lsP[4][16 * 64];
  const u16* kfb = kb + (size_t)bh * 2048 * 64;
  const u16* vfb = vtb + (size_t)bh * 64 * 2048;

  int ci0 = tid, ci1 = 256 + tid;
  int r0 = ci0 >> 3, cb0 = ci0 & 7, sw0 = (cb0 * 8) ^ ((r0 & 7) * 8);
  int r1 = ci1 >> 3, cb1 = ci1 & 7, sw1 = (cb1 * 8) ^ ((r1 & 7) * 8);

#define STAGE(buf, kf_)                                                        \
  do {                                                                         \
    const u16* kp = kfb + (size_t)(kf_) * 64 * 64;                             \
    llds16(&lsK[buf][ci0 * 8], &kp[(size_t)r0 * 64 + sw0]);                    \
    llds16(&lsK[buf][ci1 * 8], &kp[(size_t)r1 * 64 + sw1]);                    \
    llds16(&lsV[buf][ci0 * 8], &vfb[(size_t)r0 * 2048 + (kf_) * 64 + sw0]);    \
    llds16(&lsV[buf][ci1 * 8], &vfb[(size_t)r1 * 2048 + (kf_) * 64 + sw1]);    \
  } while (0)

  STAGE(0, 0);

  int qrow = wave * 16 + lr;
  const u16* qbA = qb + ((size_t)bh * 2048 + qfA * 64) * 64;
  const u16* qbB = qb + ((size_t)bh * 2048 + qfB * 64) * 64;
  bf16x8 qaA0 = *(const bf16x8*)&qbA[qrow * 64 + lq * 8];
  bf16x8 qaA1 = *(const bf16x8*)&qbA[qrow * 64 + 32 + lq * 8];
  bf16x8 qaB0 = *(const bf16x8*)&qbB[qrow * 64 + lq * 8];
  bf16x8 qaB1 = *(const bf16x8*)&qbB[qrow * 64 + 32 + lq * 8];

  f32x4 oA[4] = {}, oB[4] = {};
  float mA = -1e30f, lA = 0.f, mB = -1e30f, lB = 0.f;
  u16* pw = lsP[wave];

  for (int kf = 0; kf <= qfA; ++kf) {
    int cur = kf & 1;
    bool dual = (kf <= qfB);
    if (kf < qfA) {
      STAGE(cur ^ 1, kf + 1);
      VMW(4);  // my 4 loads for buf[cur] complete; next tile's stay in flight
    } else {
      VMW(0);
    }
    BARRIER();
    // S^T = K.Q^T for A (and B when dual); K fragments shared
    f32x4 sA[4], sB[4];
    __builtin_amdgcn_s_setprio(1);
#pragma unroll
    for (int c = 0; c < 4; ++c) {
      int rk = c * 16 + lr;
      bf16x8 k0 = *(const bf16x8*)&lsK[cur][rk * 64 + SWZ8(rk, lq * 8)];
      bf16x8 k1 = *(const bf16x8*)&lsK[cur][rk * 64 + SWZ8(rk, 32 + lq * 8)];
      f32x4 zA = {};
      zA = MFMA16(k0, qaA0, zA);
      zA = MFMA16(k1, qaA1, zA);
      sA[c] = zA;
      if (dual) {
        f32x4 zB = {};
        zB = MFMA16(k0, qaB0, zB);
        zB = MFMA16(k1, qaB1, zB);
        sB[c] = zB;
      }
    }
    __builtin_amdgcn_s_setprio(0);

    // ---- softmax + P-pack for A (exp2 domain; q = lr lane-local) ----
    bf16x8 paA0, paA1, paB0, paB1;
    {
      float m0 = fmaxf(fmaxf(sA[0][0], sA[0][1]), fmaxf(sA[0][2], sA[0][3]));
      float m1 = fmaxf(fmaxf(sA[1][0], sA[1][1]), fmaxf(sA[1][2], sA[1][3]));
      float m2 = fmaxf(fmaxf(sA[2][0], sA[2][1]), fmaxf(sA[2][2], sA[2][3]));
      float m3 = fmaxf(fmaxf(sA[3][0], sA[3][1]), fmaxf(sA[3][2], sA[3][3]));
      float mx = fmaxf(fmaxf(m0, m1), fmaxf(m2, m3));
      mx = fmaxf(mx, __shfl_xor(mx, 16, 64));
      mx = fmaxf(mx, __shfl_xor(mx, 32, 64));
      float mn = fmaxf(mA, mx);
      float al = exp2_hw(mA - mn);
      mA = mn;
      float sum = 0.f;
#pragma unroll
      for (int c = 0; c < 4; ++c)
#pragma unroll
        for (int r = 0; r < 4; ++r) {
          sA[c][r] = exp2_hw(sA[c][r] - mn);
          sum += sA[c][r];
        }
      sum += __shfl_xor(sum, 16, 64);
      sum += __shfl_xor(sum, 32, 64);
      lA = lA * al + sum;
      float al0 = __shfl(al, lq * 4 + 0, 64);
      float al1 = __shfl(al, lq * 4 + 1, 64);
      float al2 = __shfl(al, lq * 4 + 2, 64);
      float al3 = __shfl(al, lq * 4 + 3, 64);
#pragma unroll
      for (int oc = 0; oc < 4; ++oc) {
        oA[oc][0] *= al0;
        oA[oc][1] *= al1;
        oA[oc][2] *= al2;
        oA[oc][3] *= al3;
      }
#pragma unroll
      for (int c = 0; c < 4; ++c) {
        union { unsigned u[2]; uint2 q2; } pk;
        pk.u[0] = cvtpk(sA[c][0], sA[c][1]);
        pk.u[1] = cvtpk(sA[c][2], sA[c][3]);
        *(uint2*)&pw[lr * 64 + ((c * 16 + lq * 4) ^ ((lr & 7) * 8))] = pk.q2;
      }
      paA0 = *(const bf16x8*)&pw[lr * 64 + SWZ8(lr, lq * 8)];
      paA1 = *(const bf16x8*)&pw[lr * 64 + SWZ8(lr, 32 + lq * 8)];
    }
    // ---- softmax + P-pack for B (after P_A readback; same buffer) ----
    if (dual) {
      float m0 = fmaxf(fmaxf(sB[0][0], sB[0][1]), fmaxf(sB[0][2], sB[0][3]));
      float m1 = fmaxf(fmaxf(sB[1][0], sB[1][1]), fmaxf(sB[1][2], sB[1][3]));
      float m2 = fmaxf(fmaxf(sB[2][0], sB[2][1]), fmaxf(sB[2][2], sB[2][3]));
      float m3 = fmaxf(fmaxf(sB[3][0], sB[3][1]), fmaxf(sB[3][2], sB[3][3]));
      float mx = fmaxf(fmaxf(m0, m1), fmaxf(m2, m3));
      mx = fmaxf(mx, __shfl_xor(mx, 16, 64));
      mx = fmaxf(mx, __shfl_xor(mx, 32, 64));
      float mn = fmaxf(mB, mx);
      float al = exp2_hw(mB - mn);
      mB = mn;
      float sum = 0.f;
#pragma unroll
      for (int c = 0; c < 4; ++c)
#pragma unroll
        for (int r = 0; r < 4; ++r) {
          sB[c][r] = exp2_hw(sB[c][r] - mn);
          sum += sB[c][r];
        }
      sum += __shfl_xor(sum, 16, 64);
      sum += __shfl_xor(sum, 32, 64);
      lB = lB * al + sum;
      float al0 = __shfl(al, lq * 4 + 0, 64);
      float al1 = __shfl(al, lq * 4 + 1, 64);
      float al2 = __shfl(al, lq * 4 + 2, 64);
      float al3 = __shfl(al, lq * 4 + 3, 64);
#pragma unroll
      for (int oc = 0; oc < 4; ++oc) {
        oB[oc][0] *= al0;
        oB[oc][1] *= al1;
        oB[oc][2] *= al2;
        oB[oc][3] *= al3;
      }
#pragma unroll
      for (int c = 0; c < 4; ++c) {
        union { unsigned u[2]; uint2 q2; } pk;
        pk.u[0] = cvtpk(sB[c][0], sB[c][1]);
        pk.u[1] = cvtpk(sB[c][2], sB[c][3]);
        *(uint2*)&pw[lr * 64 + ((c * 16 + lq * 4) ^ ((lr & 7) * 8))] = pk.q2;
      }
      paB0 = *(const bf16x8*)&pw[lr * 64 + SWZ8(lr, lq * 8)];
      paB1 = *(const bf16x8*)&pw[lr * 64 + SWZ8(lr, 32 + lq * 8)];
    }
    // ---- PV for both frames; V fragments read once ----
    __builtin_amdgcn_s_setprio(1);
#pragma unroll
    for (int oc = 0; oc < 4; ++oc) {
      int rv = oc * 16 + lr;
      bf16x8 v0 = *(const bf16x8*)&lsV[cur][rv * 64 + SWZ8(rv, lq * 8)];
      bf16x8 v1 = *(const bf16x8*)&lsV[cur][rv * 64 + SWZ8(rv, 32 + lq * 8)];
      oA[oc] = MFMA16(paA0, v0, oA[oc]);
      oA[oc] = MFMA16(paA1, v1, oA[oc]);
      if (dual) {
        oB[oc] = MFMA16(paB0, v0, oB[oc]);
        oB[oc] = MFMA16(paB1, v1, oB[oc]);
      }
    }
    __builtin_amdgcn_s_setprio(0);
    BARRIER();
  }
#undef STAGE
  int b = bh >> 3, h = bh & 7;
  // frame A epilogue
  {
    float inv = 1.0f / lA;
    float i0 = __shfl(inv, lq * 4 + 0, 64);
    float i1 = __shfl(inv, lq * 4 + 1, 64);
    float i2 = __shfl(inv, lq * 4 + 2, 64);
    float i3 = __shfl(inv, lq * 4 + 3, 64);
#pragma unroll
    for (int oc = 0; oc < 4; ++oc) {
      int q = qfA * 64 + wave * 16 + lq * 4;
      int col = h * 64 + oc * 16 + lr;
      ao[((size_t)b * 2048 + q + 0) * 512 + col] = f2bf(oA[oc][0] * i0);
      ao[((size_t)b * 2048 + q + 1) * 512 + col] = f2bf(oA[oc][1] * i1);
      ao[((size_t)b * 2048 + q + 2) * 512 + col] = f2bf(oA[oc][2] * i2);
      ao[((size_t)b * 2048 + q + 3) * 512 + col] = f2bf(oA[oc][3] * i3);
    }
  }
  // frame B epilogue
  {
    float inv = 1.0f / lB;
    float i0 = __shfl(inv, lq * 4 + 0, 64);
    float i1 = __shfl(inv, lq * 4 + 1, 64);
    float i2 = __shfl(inv, lq * 4 + 2, 64);
    float i3 = __shfl(inv, lq * 4 + 3, 64);
#pragma unroll
    for (int oc = 0; oc < 4; ++oc) {
      int q = qfB * 64 + wave * 16 + lq * 4;
      int col = h * 64 + oc * 16 + lr;
      ao[((size_t)b * 2048 + q + 0) * 512 + col] = f2bf(oB[oc][0] * i0);
      ao[((size_t)b * 2048 + q + 1) * 512 + col] = f2bf(oB[oc][1] * i1);
      ao[((size_t)b * 2048 + q + 2) * 512 + col] = f2bf(oB[oc][2] * i2);
      ao[((size_t)b * 2048 + q + 3) * 512 + col] = f2bf(oB[oc][3] * i3);
    }
  }
}

// ---------------- out GEMM: [8192,512] x [512,512] + bias -> fp32 ----------------
__global__ __launch_bounds__(256) void gemm_out(
    const u16* __restrict__ A, const u16* __restrict__ BT,
    const float* __restrict__ bias, float* __restrict__ out) {
  __shared__ u16 lsA[128 * 64], lsB[128 * 64];
  int m0 = blockIdx.x * 128, n0 = blockIdx.y * 128;
  int tid = threadIdx.x;
  int lane = tid & 63, wave = tid >> 6;
  int wm = (wave >> 1) * 64, wn = (wave & 1) * 64;
  int lr = lane & 15, lq = lane >> 4;
  f32x4 acc[4][4] = {};
  for (int kt = 0; kt < 8; ++kt) {
#pragma unroll
    for (int c = 0; c < 4; ++c) {
      int ci = c * 256 + tid;
      int row = ci >> 3, colb = ci & 7;
      int goff = kt * 64 + ((colb * 8) ^ ((row & 7) * 8));
      llds16(&lsA[ci * 8], &A[(size_t)(m0 + row) * 512 + goff]);
      llds16(&lsB[ci * 8], &BT[(size_t)(n0 + row) * 512 + goff]);
    }
    __syncthreads();
#pragma unroll
    for (int ks = 0; ks < 2; ++ks) {
      bf16x8 af[4], bfr[4];
#pragma unroll
      for (int i = 0; i < 4; ++i) {
        int ra = wm + i * 16 + lr;
        af[i] = *(const bf16x8*)&lsA[ra * 64 + SWZ8(ra, ks * 32 + lq * 8)];
        int rb = wn + i * 16 + lr;
        bfr[i] = *(const bf16x8*)&lsB[rb * 64 + SWZ8(rb, ks * 32 + lq * 8)];
      }
#pragma unroll
      for (int i = 0; i < 4; ++i)
#pragma unroll
        for (int j = 0; j < 4; ++j)
          acc[i][j] = MFMA16(af[i], bfr[j], acc[i][j]);
    }
    __syncthreads();
  }
#pragma unroll
  for (int j = 0; j < 4; ++j) {
    int gn = n0 + wn + j * 16 + lr;
    float bj = bias[gn];
#pragma unroll
    for (int i = 0; i < 4; ++i) {
      int gm = m0 + wm + i * 16 + lq * 4;
#pragma unroll
      for (int r = 0; r < 4; ++r)
        out[(size_t)(gm + r) * 512 + gn] = acc[i][j][r] + bj;
    }
  }
}

extern "C" void kernel_launch(void* const* d_in, const int* in_sizes, int n_in,
                              void* d_out, int out_size, void* d_ws, size_t ws_size,
                              hipStream_t stream) {
  const float* x = (const float*)d_in[0];
  const float* ln_g = (const float*)d_in[1];
  const float* ln_b = (const float*)d_in[2];
  const float* w_qkv = (const float*)d_in[3];
  const float* w_out = (const float*)d_in[4];
  const float* b_out = (const float*)d_in[5];
  float* out = (float*)d_out;
  char* ws = (char*)d_ws;

  u16* xn    = (u16*)(ws + 0);          //  8 MB  [8192][512] bf16
  u16* wqkvT = (u16*)(ws + 8388608);    //  1.5 MB [1536][512]
  u16* woutT = (u16*)(ws + 9961472);    //  0.5 MB [512][512]
  u16* qb    = (u16*)(ws + 10485760);   //  8 MB  [B,H,T,D]
  u16* kb    = (u16*)(ws + 18874368);   //  8 MB  [B,H,T,D]
  u16* vtb   = (u16*)(ws + 27262976);   //  8 MB  [B,H,D,T]
  u16* ao    = (u16*)(ws + 35651584);   //  8 MB  [8192][512]

  prep_weights<<<4096, 256, 0, stream>>>(w_qkv, w_out, wqkvT, woutT);
  ln_kernel<<<2048, 256, 0, stream>>>(x, ln_g, ln_b, xn);
  gemm_qkv<<<dim3(64, 12), 256, 0, stream>>>(xn, wqkvT, qb, kb, vtb);
  attn_kernel<<<512, 256, 0, stream>>>(qb, kb, vtb, ao);
  gemm_out<<<dim3(64, 4), 256, 0, stream>>>(ao, woutT, b_out, out);
}

// Round 7
// 163.879 us; speedup vs baseline: 1.0440x; 1.0440x over previous
//
#include <hip/hip_runtime.h>

typedef unsigned short u16;
typedef float f32x4 __attribute__((ext_vector_type(4)));
typedef short bf16x8 __attribute__((ext_vector_type(8)));

#define MFMA16(a, b, c) __builtin_amdgcn_mfma_f32_16x16x32_bf16((a), (b), (c), 0, 0, 0)
// XOR swizzle in 16B (8-short) units within a 64-short row
#define SWZ8(row, off) ((off) ^ (((row) & 7) << 3))

#define CFENCE() asm volatile("" ::: "memory")
#define BARRIER() do { CFENCE(); __builtin_amdgcn_s_barrier(); CFENCE(); } while (0)
#define VMW(n) asm volatile("s_waitcnt vmcnt(" #n ")" ::: "memory")

// round-to-nearest-even f32 -> bf16 (software; proven rounds 0-2)
static __device__ __forceinline__ u16 f2bf(float f) {
  union { float f; unsigned u; } c; c.f = f;
  unsigned r = c.u + 0x7fffu + ((c.u >> 16) & 1u);
  return (u16)(r >> 16);
}

// hardware 2^x (v_exp_f32 IS exp2)
static __device__ __forceinline__ float exp2_hw(float x) {
  float r;
  asm("v_exp_f32 %0, %1" : "=v"(r) : "v"(x));
  return r;
}

// packed f32x2 -> bf16x2 (used ONLY for P, the tolerance-insensitive site)
static __device__ __forceinline__ unsigned cvtpk(float lo, float hi) {
  unsigned r;
  asm("v_cvt_pk_bf16_f32 %0, %1, %2" : "=v"(r) : "v"(lo), "v"(hi));
  return r;
}

static __device__ __forceinline__ void llds16(u16* l, const u16* g) {
  __builtin_amdgcn_global_load_lds((const __attribute__((address_space(1))) void*)g,
                                   (__attribute__((address_space(3))) void*)l, 16, 0, 0);
}

// ---------------- prep: LDS tile-transpose weights to bf16 [N][K] ----------------
// Coalesced float4 reads AND coalesced 16B writes; one 64x64 tile per block.
__global__ __launch_bounds__(256) void prep_weights(
    const float* __restrict__ w_qkv, const float* __restrict__ w_out,
    u16* __restrict__ wqkvT, u16* __restrict__ woutT) {
  __shared__ u16 tile[64][66];
  int bid = blockIdx.x;
  const float* src;
  u16* dst;
  int C, tr, tc;
  if (bid < 192) {  // w_qkv [512][1536] -> wqkvT [1536][512]
    src = w_qkv; dst = wqkvT; C = 1536;
    tr = (bid & 7) * 64;
    tc = (bid >> 3) * 64;
  } else {          // w_out [512][512] -> woutT [512][512]
    int b2 = bid - 192;
    src = w_out; dst = woutT; C = 512;
    tr = (b2 & 7) * 64;
    tc = (b2 >> 3) * 64;
  }
  int tid = threadIdx.x;
  int i = tid >> 4;         // row-in-pass 0..15
  int j4 = (tid & 15) * 4;  // col base
#pragma unroll
  for (int p = 0; p < 4; ++p) {
    int row = i + p * 16;
    float4 v = *(const float4*)&src[(size_t)(tr + row) * C + tc + j4];
    tile[row][j4 + 0] = f2bf(v.x);
    tile[row][j4 + 1] = f2bf(v.y);
    tile[row][j4 + 2] = f2bf(v.z);
    tile[row][j4 + 3] = f2bf(v.w);
  }
  __syncthreads();
  int j = tid >> 3;        // out-row-in-pass 0..31
  int i8 = (tid & 7) * 8;  // out-col base
#pragma unroll
  for (int p = 0; p < 2; ++p) {
    int orow = j + p * 32;
    union { u16 h[8]; uint4 q; } o;
#pragma unroll
    for (int s = 0; s < 8; ++s) o.h[s] = tile[i8 + s][orow];
    *(uint4*)&dst[(size_t)(tc + orow) * 512 + tr + i8] = o.q;
  }
}

// ---------------- LayerNorm -> bf16 (one wave per row; f2bf rounding) ----------------
__global__ __launch_bounds__(256) void ln_kernel(
    const float* __restrict__ x, const float* __restrict__ g,
    const float* __restrict__ be, u16* __restrict__ xn) {
  int row = blockIdx.x * 4 + (threadIdx.x >> 6);
  int lane = threadIdx.x & 63;
  const float4* xr = (const float4*)(x + (size_t)row * 512) + lane * 2;
  float4 v0 = xr[0], v1 = xr[1];
  float s = v0.x + v0.y + v0.z + v0.w + v1.x + v1.y + v1.z + v1.w;
  float ss = v0.x * v0.x + v0.y * v0.y + v0.z * v0.z + v0.w * v0.w +
             v1.x * v1.x + v1.y * v1.y + v1.z * v1.z + v1.w * v1.w;
#pragma unroll
  for (int msk = 32; msk >= 1; msk >>= 1) {
    s += __shfl_xor(s, msk, 64);
    ss += __shfl_xor(ss, msk, 64);
  }
  float mu = s * (1.f / 512.f);
  float var = ss * (1.f / 512.f) - mu * mu;
  float rs = rsqrtf(var + 1e-5f);
  const float4* gp = (const float4*)g + lane * 2;
  const float4* bp = (const float4*)be + lane * 2;
  float4 g0 = gp[0], g1 = gp[1], b0 = bp[0], b1 = bp[1];
  union { u16 h[8]; uint4 q; } o;
  o.h[0] = f2bf((v0.x - mu) * rs * g0.x + b0.x);
  o.h[1] = f2bf((v0.y - mu) * rs * g0.y + b0.y);
  o.h[2] = f2bf((v0.z - mu) * rs * g0.z + b0.z);
  o.h[3] = f2bf((v0.w - mu) * rs * g0.w + b0.w);
  o.h[4] = f2bf((v1.x - mu) * rs * g1.x + b1.x);
  o.h[5] = f2bf((v1.y - mu) * rs * g1.y + b1.y);
  o.h[6] = f2bf((v1.z - mu) * rs * g1.z + b1.z);
  o.h[7] = f2bf((v1.w - mu) * rs * g1.w + b1.w);
  *(uint4*)&xn[(size_t)row * 512 + lane * 8] = o.q;
}

// ---------------- QKV GEMM: [8192,512] x [512,1536], scatter q/k/vT ----------------
// q pre-scaled by 0.125 * log2(e) so attention softmax runs in exp2 domain.
// XCD-partitioned grid: XCD i owns m-tiles [8i, 8i+8) x all n -> per-XCD
// working set 1MB A-panel + 1.5MB B = L2-resident; A fetched ~once.
__global__ __launch_bounds__(256) void gemm_qkv(
    const u16* __restrict__ A, const u16* __restrict__ BT,
    u16* __restrict__ qb, u16* __restrict__ kb, u16* __restrict__ vtb) {
  __shared__ u16 lsA[128 * 64], lsB[128 * 64];
  int bid = blockIdx.x;
  int xcd = bid & 7, sq = bid >> 3;       // sq 0..95
  int m0 = (xcd * 8 + (sq & 7)) * 128;    // 64 m-tiles
  int n0 = (sq >> 3) * 128;               // 12 n-tiles
  int tid = threadIdx.x;
  int lane = tid & 63, wave = tid >> 6;
  int wm = (wave >> 1) * 64, wn = (wave & 1) * 64;
  int lr = lane & 15, lq = lane >> 4;
  f32x4 acc[4][4] = {};
  for (int kt = 0; kt < 8; ++kt) {
#pragma unroll
    for (int c = 0; c < 4; ++c) {
      int ci = c * 256 + tid;
      int row = ci >> 3, colb = ci & 7;
      int goff = kt * 64 + ((colb * 8) ^ ((row & 7) * 8));
      llds16(&lsA[ci * 8], &A[(size_t)(m0 + row) * 512 + goff]);
      llds16(&lsB[ci * 8], &BT[(size_t)(n0 + row) * 512 + goff]);
    }
    __syncthreads();
#pragma unroll
    for (int ks = 0; ks < 2; ++ks) {
      bf16x8 af[4], bfr[4];
#pragma unroll
      for (int i = 0; i < 4; ++i) {
        int ra = wm + i * 16 + lr;
        af[i] = *(const bf16x8*)&lsA[ra * 64 + SWZ8(ra, ks * 32 + lq * 8)];
        int rb = wn + i * 16 + lr;
        bfr[i] = *(const bf16x8*)&lsB[rb * 64 + SWZ8(rb, ks * 32 + lq * 8)];
      }
#pragma unroll
      for (int i = 0; i < 4; ++i)
#pragma unroll
        for (int j = 0; j < 4; ++j)
          acc[i][j] = MFMA16(af[i], bfr[j], acc[i][j]);
    }
    __syncthreads();
  }
  // epilogue: n<512 -> q (scaled), <1024 -> k, else v transposed [B,H,D,T]
#pragma unroll
  for (int j = 0; j < 4; ++j) {
    int gn = n0 + wn + j * 16 + lr;
    int sec = gn >> 9;
    int h = (gn >> 6) & 7;
    int d = gn & 63;
#pragma unroll
    for (int i = 0; i < 4; ++i) {
      int gm = m0 + wm + i * 16 + lq * 4;
      int b = gm >> 11, t0 = gm & 2047;
      int bh = b * 8 + h;
      if (sec == 0) {
#pragma unroll
        for (int r = 0; r < 4; ++r)
          qb[((size_t)bh * 2048 + t0 + r) * 64 + d] = f2bf(acc[i][j][r] * 0.180336880f);
      } else if (sec == 1) {
#pragma unroll
        for (int r = 0; r < 4; ++r)
          kb[((size_t)bh * 2048 + t0 + r) * 64 + d] = f2bf(acc[i][j][r]);
      } else {
        ushort4 pk;
        pk.x = f2bf(acc[i][j][0]);
        pk.y = f2bf(acc[i][j][1]);
        pk.z = f2bf(acc[i][j][2]);
        pk.w = f2bf(acc[i][j][3]);
        *(ushort4*)&vtb[((size_t)bh * 64 + d) * 2048 + t0] = pk;
      }
    }
  }
}

// ---------------- frame-causal flash attention (round-5 structure) ----------------
// Swapped QK^T: S^T = mfma(K,Q) -> lane-local softmax for q = lane&15 in the
// exp2 domain (log2e folded into q). P via proven wave-private LDS path with
// packed cvtpk writes; PV/epilogue round-2 verbatim 16x16x32 MFMA.
__global__ __launch_bounds__(256) void attn_kernel(
    const u16* __restrict__ qb, const u16* __restrict__ kb,
    const u16* __restrict__ vtb, u16* __restrict__ ao) {
  int blk = blockIdx.x;
  int xcd = blk & 7;
  int seq = blk >> 3;            // 0..127
  int bh = xcd * 4 + (seq & 3);  // 4 bh per XCD -> L2-resident K/V
  int qf = 31 - (seq >> 2);      // heavy frames first
  int tid = threadIdx.x, lane = tid & 63, wave = tid >> 6;
  int lr = lane & 15, lq = lane >> 4;
  __shared__ u16 lsK[2][64 * 64], lsV[2][64 * 64];
  __shared__ u16 lsP[4][16 * 64];
  const u16* kfb = kb + (size_t)bh * 2048 * 64;
  const u16* vfb = vtb + (size_t)bh * 64 * 2048;

  int ci0 = tid, ci1 = 256 + tid;
  int r0 = ci0 >> 3, cb0 = ci0 & 7, sw0 = (cb0 * 8) ^ ((r0 & 7) * 8);
  int r1 = ci1 >> 3, cb1 = ci1 & 7, sw1 = (cb1 * 8) ^ ((r1 & 7) * 8);

#define STAGE(buf, kf_)                                                        \
  do {                                                                         \
    const u16* kp = kfb + (size_t)(kf_) * 64 * 64;                             \
    llds16(&lsK[buf][ci0 * 8], &kp[(size_t)r0 * 64 + sw0]);                    \
    llds16(&lsK[buf][ci1 * 8], &kp[(size_t)r1 * 64 + sw1]);                    \
    llds16(&lsV[buf][ci0 * 8], &vfb[(size_t)r0 * 2048 + (kf_) * 64 + sw0]);    \
    llds16(&lsV[buf][ci1 * 8], &vfb[(size_t)r1 * 2048 + (kf_) * 64 + sw1]);    \
  } while (0)

  STAGE(0, 0);

  const u16* qbase = qb + ((size_t)bh * 2048 + qf * 64) * 64;
  int qrow = wave * 16 + lr;
  bf16x8 qa0 = *(const bf16x8*)&qbase[qrow * 64 + lq * 8];
  bf16x8 qa1 = *(const bf16x8*)&qbase[qrow * 64 + 32 + lq * 8];

  f32x4 o[4] = {};
  float m = -1e30f, l = 0.f;
  u16* pw = lsP[wave];

  for (int kf = 0; kf <= qf; ++kf) {
    int cur = kf & 1;
    if (kf < qf) {
      STAGE(cur ^ 1, kf + 1);
      VMW(4);  // my 4 loads for buf[cur] complete; next tile's stay in flight
    } else {
      VMW(0);
    }
    BARRIER();
    // S^T[k][q] = K.Q^T : lane holds k = 16c + 4*lq + r for its q = lr
    f32x4 s[4];
    __builtin_amdgcn_s_setprio(1);
#pragma unroll
    for (int c = 0; c < 4; ++c) {
      int rk = c * 16 + lr;
      bf16x8 k0 = *(const bf16x8*)&lsK[cur][rk * 64 + SWZ8(rk, lq * 8)];
      bf16x8 k1 = *(const bf16x8*)&lsK[cur][rk * 64 + SWZ8(rk, 32 + lq * 8)];
      f32x4 z = {};
      z = MFMA16(k0, qa0, z);
      z = MFMA16(k1, qa1, z);
      s[c] = z;
    }
    __builtin_amdgcn_s_setprio(0);
    // in-lane softmax for q = lr (exp2 domain)
    float m0 = fmaxf(fmaxf(s[0][0], s[0][1]), fmaxf(s[0][2], s[0][3]));
    float m1 = fmaxf(fmaxf(s[1][0], s[1][1]), fmaxf(s[1][2], s[1][3]));
    float m2 = fmaxf(fmaxf(s[2][0], s[2][1]), fmaxf(s[2][2], s[2][3]));
    float m3 = fmaxf(fmaxf(s[3][0], s[3][1]), fmaxf(s[3][2], s[3][3]));
    float mx = fmaxf(fmaxf(m0, m1), fmaxf(m2, m3));
    mx = fmaxf(mx, __shfl_xor(mx, 16, 64));
    mx = fmaxf(mx, __shfl_xor(mx, 32, 64));
    float mn = fmaxf(m, mx);
    float al = exp2_hw(m - mn);
    m = mn;
    float sum = 0.f;
#pragma unroll
    for (int c = 0; c < 4; ++c) {
#pragma unroll
      for (int r = 0; r < 4; ++r) {
        s[c][r] = exp2_hw(s[c][r] - mn);
        sum += s[c][r];
      }
    }
    sum += __shfl_xor(sum, 16, 64);
    sum += __shfl_xor(sum, 32, 64);
    l = l * al + sum;
    // redistribute al to this lane's OUTPUT rows q = 4*lq + r (held at lane q)
    float al0 = __shfl(al, lq * 4 + 0, 64);
    float al1 = __shfl(al, lq * 4 + 1, 64);
    float al2 = __shfl(al, lq * 4 + 2, 64);
    float al3 = __shfl(al, lq * 4 + 3, 64);
#pragma unroll
    for (int oc = 0; oc < 4; ++oc) {
      o[oc][0] *= al0;
      o[oc][1] *= al1;
      o[oc][2] *= al2;
      o[oc][3] *= al3;
    }
    // P -> wave-private swizzled LDS (packed 8B writes)
#pragma unroll
    for (int c = 0; c < 4; ++c) {
      union { unsigned u[2]; uint2 q2; } pk;
      pk.u[0] = cvtpk(s[c][0], s[c][1]);
      pk.u[1] = cvtpk(s[c][2], s[c][3]);
      *(uint2*)&pw[lr * 64 + ((c * 16 + lq * 4) ^ ((lr & 7) * 8))] = pk.q2;
    }
    bf16x8 pa0 = *(const bf16x8*)&pw[lr * 64 + SWZ8(lr, lq * 8)];
    bf16x8 pa1 = *(const bf16x8*)&pw[lr * 64 + SWZ8(lr, 32 + lq * 8)];
    // O += P V
    __builtin_amdgcn_s_setprio(1);
#pragma unroll
    for (int oc = 0; oc < 4; ++oc) {
      int rv = oc * 16 + lr;
      bf16x8 v0 = *(const bf16x8*)&lsV[cur][rv * 64 + SWZ8(rv, lq * 8)];
      bf16x8 v1 = *(const bf16x8*)&lsV[cur][rv * 64 + SWZ8(rv, 32 + lq * 8)];
      o[oc] = MFMA16(pa0, v0, o[oc]);
      o[oc] = MFMA16(pa1, v1, o[oc]);
    }
    __builtin_amdgcn_s_setprio(0);
    BARRIER();
  }
#undef STAGE
  // redistribute 1/l to output rows (lane q holds l for q = lane&15)
  float inv = 1.0f / l;
  float i0 = __shfl(inv, lq * 4 + 0, 64);
  float i1 = __shfl(inv, lq * 4 + 1, 64);
  float i2 = __shfl(inv, lq * 4 + 2, 64);
  float i3 = __shfl(inv, lq * 4 + 3, 64);
  int b = bh >> 3, h = bh & 7;
#pragma unroll
  for (int oc = 0; oc < 4; ++oc) {
    int q = qf * 64 + wave * 16 + lq * 4;
    int col = h * 64 + oc * 16 + lr;
    ao[((size_t)b * 2048 + q + 0) * 512 + col] = f2bf(o[oc][0] * i0);
    ao[((size_t)b * 2048 + q + 1) * 512 + col] = f2bf(o[oc][1] * i1);
    ao[((size_t)b * 2048 + q + 2) * 512 + col] = f2bf(o[oc][2] * i2);
    ao[((size_t)b * 2048 + q + 3) * 512 + col] = f2bf(o[oc][3] * i3);
  }
}

// ---------------- out GEMM: [8192,512] x [512,512] + bias -> fp32 ----------------
// XCD-partitioned: XCD i owns m-tiles [8i, 8i+8) x all 4 n-tiles.
__global__ __launch_bounds__(256) void gemm_out(
    const u16* __restrict__ A, const u16* __restrict__ BT,
    const float* __restrict__ bias, float* __restrict__ out) {
  __shared__ u16 lsA[128 * 64], lsB[128 * 64];
  int bid = blockIdx.x;
  int xcd = bid & 7, sq = bid >> 3;     // sq 0..31
  int m0 = (xcd * 8 + (sq & 7)) * 128;  // 64 m-tiles
  int n0 = (sq >> 3) * 128;             // 4 n-tiles
  int tid = threadIdx.x;
  int lane = tid & 63, wave = tid >> 6;
  int wm = (wave >> 1) * 64, wn = (wave & 1) * 64;
  int lr = lane & 15, lq = lane >> 4;
  f32x4 acc[4][4] = {};
  for (int kt = 0; kt < 8; ++kt) {
#pragma unroll
    for (int c = 0; c < 4; ++c) {
      int ci = c * 256 + tid;
      int row = ci >> 3, colb = ci & 7;
      int goff = kt * 64 + ((colb * 8) ^ ((row & 7) * 8));
      llds16(&lsA[ci * 8], &A[(size_t)(m0 + row) * 512 + goff]);
      llds16(&lsB[ci * 8], &BT[(size_t)(n0 + row) * 512 + goff]);
    }
    __syncthreads();
#pragma unroll
    for (int ks = 0; ks < 2; ++ks) {
      bf16x8 af[4], bfr[4];
#pragma unroll
      for (int i = 0; i < 4; ++i) {
        int ra = wm + i * 16 + lr;
        af[i] = *(const bf16x8*)&lsA[ra * 64 + SWZ8(ra, ks * 32 + lq * 8)];
        int rb = wn + i * 16 + lr;
        bfr[i] = *(const bf16x8*)&lsB[rb * 64 + SWZ8(rb, ks * 32 + lq * 8)];
      }
#pragma unroll
      for (int i = 0; i < 4; ++i)
#pragma unroll
        for (int j = 0; j < 4; ++j)
          acc[i][j] = MFMA16(af[i], bfr[j], acc[i][j]);
    }
    __syncthreads();
  }
#pragma unroll
  for (int j = 0; j < 4; ++j) {
    int gn = n0 + wn + j * 16 + lr;
    float bj = bias[gn];
#pragma unroll
    for (int i = 0; i < 4; ++i) {
      int gm = m0 + wm + i * 16 + lq * 4;
#pragma unroll
      for (int r = 0; r < 4; ++r)
        out[(size_t)(gm + r) * 512 + gn] = acc[i][j][r] + bj;
    }
  }
}

extern "C" void kernel_launch(void* const* d_in, const int* in_sizes, int n_in,
                              void* d_out, int out_size, void* d_ws, size_t ws_size,
                              hipStream_t stream) {
  const float* x = (const float*)d_in[0];
  const float* ln_g = (const float*)d_in[1];
  const float* ln_b = (const float*)d_in[2];
  const float* w_qkv = (const float*)d_in[3];
  const float* w_out = (const float*)d_in[4];
  const float* b_out = (const float*)d_in[5];
  float* out = (float*)d_out;
  char* ws = (char*)d_ws;

  u16* xn    = (u16*)(ws + 0);          //  8 MB  [8192][512] bf16
  u16* wqkvT = (u16*)(ws + 8388608);    //  1.5 MB [1536][512]
  u16* woutT = (u16*)(ws + 9961472);    //  0.5 MB [512][512]
  u16* qb    = (u16*)(ws + 10485760);   //  8 MB  [B,H,T,D]
  u16* kb    = (u16*)(ws + 18874368);   //  8 MB  [B,H,T,D]
  u16* vtb   = (u16*)(ws + 27262976);   //  8 MB  [B,H,D,T]
  u16* ao    = (u16*)(ws + 35651584);   //  8 MB  [8192][512]

  prep_weights<<<256, 256, 0, stream>>>(w_qkv, w_out, wqkvT, woutT);
  ln_kernel<<<2048, 256, 0, stream>>>(x, ln_g, ln_b, xn);
  gemm_qkv<<<768, 256, 0, stream>>>(xn, wqkvT, qb, kb, vtb);
  attn_kernel<<<1024, 256, 0, stream>>>(qb, kb, vtb, ao);
  gemm_out<<<256, 256, 0, stream>>>(ao, woutT, b_out, out);
}

// Round 8
// 159.491 us; speedup vs baseline: 1.0727x; 1.0275x over previous
//
#include <hip/hip_runtime.h>

typedef unsigned short u16;
typedef float f32x4 __attribute__((ext_vector_type(4)));
typedef short bf16x8 __attribute__((ext_vector_type(8)));

#define MFMA16(a, b, c) __builtin_amdgcn_mfma_f32_16x16x32_bf16((a), (b), (c), 0, 0, 0)
// XOR swizzle in 16B (8-short) units within a 64-short row
#define SWZ8(row, off) ((off) ^ (((row) & 7) << 3))

#define CFENCE() asm volatile("" ::: "memory")
#define BARRIER() do { CFENCE(); __builtin_amdgcn_s_barrier(); CFENCE(); } while (0)
#define VMW(n) asm volatile("s_waitcnt vmcnt(" #n ")" ::: "memory")

// round-to-nearest-even f32 -> bf16 (software; proven rounds 0-2)
static __device__ __forceinline__ u16 f2bf(float f) {
  union { float f; unsigned u; } c; c.f = f;
  unsigned r = c.u + 0x7fffu + ((c.u >> 16) & 1u);
  return (u16)(r >> 16);
}

// hardware 2^x (v_exp_f32 IS exp2)
static __device__ __forceinline__ float exp2_hw(float x) {
  float r;
  asm("v_exp_f32 %0, %1" : "=v"(r) : "v"(x));
  return r;
}

// packed f32x2 -> bf16x2 (used ONLY for P, the tolerance-insensitive site)
static __device__ __forceinline__ unsigned cvtpk(float lo, float hi) {
  unsigned r;
  asm("v_cvt_pk_bf16_f32 %0, %1, %2" : "=v"(r) : "v"(lo), "v"(hi));
  return r;
}

static __device__ __forceinline__ void llds16(u16* l, const u16* g) {
  __builtin_amdgcn_global_load_lds((const __attribute__((address_space(1))) void*)g,
                                   (__attribute__((address_space(3))) void*)l, 16, 0, 0);
}

// ---------------- fused prep (weights transpose) + LayerNorm ----------------
// blocks 0..2047: LN wave-per-row. blocks 2048..2303: 64x64 weight tile transpose.
__global__ __launch_bounds__(256) void prep_ln(
    const float* __restrict__ x, const float* __restrict__ g,
    const float* __restrict__ be, u16* __restrict__ xn,
    const float* __restrict__ w_qkv, const float* __restrict__ w_out,
    u16* __restrict__ wqkvT, u16* __restrict__ woutT) {
  __shared__ u16 tile[64][66];
  int bid = blockIdx.x;
  int tid = threadIdx.x;
  if (bid < 2048) {
    int row = bid * 4 + (tid >> 6);
    int lane = tid & 63;
    const float4* xr = (const float4*)(x + (size_t)row * 512) + lane * 2;
    float4 v0 = xr[0], v1 = xr[1];
    float s = v0.x + v0.y + v0.z + v0.w + v1.x + v1.y + v1.z + v1.w;
    float ss = v0.x * v0.x + v0.y * v0.y + v0.z * v0.z + v0.w * v0.w +
               v1.x * v1.x + v1.y * v1.y + v1.z * v1.z + v1.w * v1.w;
#pragma unroll
    for (int msk = 32; msk >= 1; msk >>= 1) {
      s += __shfl_xor(s, msk, 64);
      ss += __shfl_xor(ss, msk, 64);
    }
    float mu = s * (1.f / 512.f);
    float var = ss * (1.f / 512.f) - mu * mu;
    float rs = rsqrtf(var + 1e-5f);
    const float4* gp = (const float4*)g + lane * 2;
    const float4* bp = (const float4*)be + lane * 2;
    float4 g0 = gp[0], g1 = gp[1], b0 = bp[0], b1 = bp[1];
    union { u16 h[8]; uint4 q; } o;
    o.h[0] = f2bf((v0.x - mu) * rs * g0.x + b0.x);
    o.h[1] = f2bf((v0.y - mu) * rs * g0.y + b0.y);
    o.h[2] = f2bf((v0.z - mu) * rs * g0.z + b0.z);
    o.h[3] = f2bf((v0.w - mu) * rs * g0.w + b0.w);
    o.h[4] = f2bf((v1.x - mu) * rs * g1.x + b1.x);
    o.h[5] = f2bf((v1.y - mu) * rs * g1.y + b1.y);
    o.h[6] = f2bf((v1.z - mu) * rs * g1.z + b1.z);
    o.h[7] = f2bf((v1.w - mu) * rs * g1.w + b1.w);
    *(uint4*)&xn[(size_t)row * 512 + lane * 8] = o.q;
    return;
  }
  int pb = bid - 2048;
  const float* src;
  u16* dst;
  int C, tr, tc;
  if (pb < 192) {  // w_qkv [512][1536] -> wqkvT [1536][512]
    src = w_qkv; dst = wqkvT; C = 1536;
    tr = (pb & 7) * 64;
    tc = (pb >> 3) * 64;
  } else {         // w_out [512][512] -> woutT [512][512]
    int b2 = pb - 192;
    src = w_out; dst = woutT; C = 512;
    tr = (b2 & 7) * 64;
    tc = (b2 >> 3) * 64;
  }
  int i = tid >> 4;
  int j4 = (tid & 15) * 4;
#pragma unroll
  for (int p = 0; p < 4; ++p) {
    int row = i + p * 16;
    float4 v = *(const float4*)&src[(size_t)(tr + row) * C + tc + j4];
    tile[row][j4 + 0] = f2bf(v.x);
    tile[row][j4 + 1] = f2bf(v.y);
    tile[row][j4 + 2] = f2bf(v.z);
    tile[row][j4 + 3] = f2bf(v.w);
  }
  __syncthreads();
  int j = tid >> 3;
  int i8 = (tid & 7) * 8;
#pragma unroll
  for (int p = 0; p < 2; ++p) {
    int orow = j + p * 32;
    union { u16 h[8]; uint4 q; } o;
#pragma unroll
    for (int s = 0; s < 8; ++s) o.h[s] = tile[i8 + s][orow];
    *(uint4*)&dst[(size_t)(tc + orow) * 512 + tr + i8] = o.q;
  }
}

// ---------------- QKV GEMM: [8192,512] x [512,1536], scatter q/k/vT ----------------
// Section (q/k/v) is uniform per block (n-tiles 0-3=q, 4-7=k, 8-11=v).
// Epilogue: acc -> swizzled LDS tile [128][128] u16 (v stored transposed),
// then fully-coalesced 16B global stores. q pre-scaled by 0.125*log2(e).
__global__ __launch_bounds__(256) void gemm_qkv(
    const u16* __restrict__ A, const u16* __restrict__ BT,
    u16* __restrict__ qb, u16* __restrict__ kb, u16* __restrict__ vtb) {
  __shared__ u16 ls[16384];  // main loop: A tile = ls[0..8191], B tile = ls[8192..]
  u16* lsA = ls;
  u16* lsB = ls + 8192;
  int bid = blockIdx.x;
  int xcd = bid & 7, sq = bid >> 3;       // sq 0..95
  int m0 = (xcd * 8 + (sq & 7)) * 128;    // 64 m-tiles
  int n0 = (sq >> 3) * 128;               // 12 n-tiles
  int sec = n0 >> 9;                      // 0=q 1=k 2=v, uniform per block
  int tid = threadIdx.x;
  int lane = tid & 63, wave = tid >> 6;
  int wm = (wave >> 1) * 64, wn = (wave & 1) * 64;
  int lr = lane & 15, lq = lane >> 4;
  f32x4 acc[4][4] = {};
  for (int kt = 0; kt < 8; ++kt) {
#pragma unroll
    for (int c = 0; c < 4; ++c) {
      int ci = c * 256 + tid;
      int row = ci >> 3, colb = ci & 7;
      int goff = kt * 64 + ((colb * 8) ^ ((row & 7) * 8));
      llds16(&lsA[ci * 8], &A[(size_t)(m0 + row) * 512 + goff]);
      llds16(&lsB[ci * 8], &BT[(size_t)(n0 + row) * 512 + goff]);
    }
    __syncthreads();
#pragma unroll
    for (int ks = 0; ks < 2; ++ks) {
      bf16x8 af[4], bfr[4];
#pragma unroll
      for (int i = 0; i < 4; ++i) {
        int ra = wm + i * 16 + lr;
        af[i] = *(const bf16x8*)&lsA[ra * 64 + SWZ8(ra, ks * 32 + lq * 8)];
        int rb = wn + i * 16 + lr;
        bfr[i] = *(const bf16x8*)&lsB[rb * 64 + SWZ8(rb, ks * 32 + lq * 8)];
      }
#pragma unroll
      for (int i = 0; i < 4; ++i)
#pragma unroll
        for (int j = 0; j < 4; ++j)
          acc[i][j] = MFMA16(af[i], bfr[j], acc[i][j]);
    }
    __syncthreads();
  }
  // ---- epilogue: acc -> LDS (swizzled u16) -> coalesced 16B stores ----
  int b = m0 >> 11, t0 = m0 & 2047;
  float sc = (sec == 0) ? 0.180336880f : 1.0f;
  if (sec < 2) {
    // straight [t][n']: row = token, col = n-within-block
#pragma unroll
    for (int i = 0; i < 4; ++i)
#pragma unroll
      for (int j = 0; j < 4; ++j) {
        int col = wn + j * 16 + lr;
#pragma unroll
        for (int r = 0; r < 4; ++r) {
          int row = wm + i * 16 + lq * 4 + r;
          ls[row * 128 + (col ^ ((row & 7) << 3))] = f2bf(acc[i][j][r] * sc);
        }
      }
    __syncthreads();
    u16* dst = (sec == 0) ? qb : kb;
#pragma unroll
    for (int s = 0; s < 8; ++s) {
      int li = s * 256 + tid;
      int row = li >> 4, c8 = (li & 15) * 8;
      uint4 v = *(uint4*)&ls[row * 128 + (c8 ^ ((row & 7) << 3))];
      int gn = n0 + c8;
      int h = (gn >> 6) & 7, d = gn & 63;
      *(uint4*)&dst[((size_t)(b * 8 + h) * 2048 + t0 + row) * 64 + d] = v;
    }
  } else {
    // transposed [n'(d)][t]: for vtb [B,H,D,T]
#pragma unroll
    for (int i = 0; i < 4; ++i)
#pragma unroll
      for (int j = 0; j < 4; ++j) {
        int col = wn + j * 16 + lr;
#pragma unroll
        for (int r = 0; r < 4; ++r) {
          int row = wm + i * 16 + lq * 4 + r;
          ls[col * 128 + (row ^ ((col & 7) << 3))] = f2bf(acc[i][j][r]);
        }
      }
    __syncthreads();
#pragma unroll
    for (int s = 0; s < 8; ++s) {
      int li = s * 256 + tid;
      int dcol = li >> 4, t8 = (li & 15) * 8;
      uint4 v = *(uint4*)&ls[dcol * 128 + (t8 ^ ((dcol & 7) << 3))];
      int gn = n0 + dcol;
      int h = (gn >> 6) & 7, d = gn & 63;
      *(uint4*)&vtb[((size_t)(b * 8 + h) * 64 + d) * 2048 + t0 + t8] = v;
    }
  }
}

// ---------------- frame-causal flash attention (R5 structure + defer-max) ----------------
// Swapped QK^T: S^T = mfma(K,Q) -> lane-local softmax for q = lane&15 in the
// exp2 domain. Defer-max (T13, THR=8): skip O-rescale when tile max doesn't
// exceed running max by >8. P via proven wave-private LDS path.
__global__ __launch_bounds__(256) void attn_kernel(
    const u16* __restrict__ qb, const u16* __restrict__ kb,
    const u16* __restrict__ vtb, u16* __restrict__ ao) {
  int blk = blockIdx.x;
  int xcd = blk & 7;
  int seq = blk >> 3;            // 0..127
  int bh = xcd * 4 + (seq & 3);  // 4 bh per XCD -> L2-resident K/V
  int qf = 31 - (seq >> 2);      // heavy frames first
  int tid = threadIdx.x, lane = tid & 63, wave = tid >> 6;
  int lr = lane & 15, lq = lane >> 4;
  __shared__ u16 lsK[2][64 * 64], lsV[2][64 * 64];
  __shared__ u16 lsP[4][16 * 64];
  const u16* kfb = kb + (size_t)bh * 2048 * 64;
  const u16* vfb = vtb + (size_t)bh * 64 * 2048;

  int ci0 = tid, ci1 = 256 + tid;
  int r0 = ci0 >> 3, cb0 = ci0 & 7, sw0 = (cb0 * 8) ^ ((r0 & 7) * 8);
  int r1 = ci1 >> 3, cb1 = ci1 & 7, sw1 = (cb1 * 8) ^ ((r1 & 7) * 8);

#define STAGE(buf, kf_)                                                        \
  do {                                                                         \
    const u16* kp = kfb + (size_t)(kf_) * 64 * 64;                             \
    llds16(&lsK[buf][ci0 * 8], &kp[(size_t)r0 * 64 + sw0]);                    \
    llds16(&lsK[buf][ci1 * 8], &kp[(size_t)r1 * 64 + sw1]);                    \
    llds16(&lsV[buf][ci0 * 8], &vfb[(size_t)r0 * 2048 + (kf_) * 64 + sw0]);    \
    llds16(&lsV[buf][ci1 * 8], &vfb[(size_t)r1 * 2048 + (kf_) * 64 + sw1]);    \
  } while (0)

  STAGE(0, 0);

  const u16* qbase = qb + ((size_t)bh * 2048 + qf * 64) * 64;
  int qrow = wave * 16 + lr;
  bf16x8 qa0 = *(const bf16x8*)&qbase[qrow * 64 + lq * 8];
  bf16x8 qa1 = *(const bf16x8*)&qbase[qrow * 64 + 32 + lq * 8];

  f32x4 o[4] = {};
  float m = -1e30f, l = 0.f;
  u16* pw = lsP[wave];

  for (int kf = 0; kf <= qf; ++kf) {
    int cur = kf & 1;
    if (kf < qf) {
      STAGE(cur ^ 1, kf + 1);
      VMW(4);  // my 4 loads for buf[cur] complete; next tile's stay in flight
    } else {
      VMW(0);
    }
    BARRIER();
    // S^T[k][q] = K.Q^T : lane holds k = 16c + 4*lq + r for its q = lr
    f32x4 s[4];
    __builtin_amdgcn_s_setprio(1);
#pragma unroll
    for (int c = 0; c < 4; ++c) {
      int rk = c * 16 + lr;
      bf16x8 k0 = *(const bf16x8*)&lsK[cur][rk * 64 + SWZ8(rk, lq * 8)];
      bf16x8 k1 = *(const bf16x8*)&lsK[cur][rk * 64 + SWZ8(rk, 32 + lq * 8)];
      f32x4 z = {};
      z = MFMA16(k0, qa0, z);
      z = MFMA16(k1, qa1, z);
      s[c] = z;
    }
    __builtin_amdgcn_s_setprio(0);
    // in-lane softmax for q = lr (exp2 domain)
    float m0 = fmaxf(fmaxf(s[0][0], s[0][1]), fmaxf(s[0][2], s[0][3]));
    float m1 = fmaxf(fmaxf(s[1][0], s[1][1]), fmaxf(s[1][2], s[1][3]));
    float m2 = fmaxf(fmaxf(s[2][0], s[2][1]), fmaxf(s[2][2], s[2][3]));
    float m3 = fmaxf(fmaxf(s[3][0], s[3][1]), fmaxf(s[3][2], s[3][3]));
    float mx = fmaxf(fmaxf(m0, m1), fmaxf(m2, m3));
    mx = fmaxf(mx, __shfl_xor(mx, 16, 64));
    mx = fmaxf(mx, __shfl_xor(mx, 32, 64));
    // defer-max: only rescale when the tile max grows past m + 8
    if (!__all(mx <= m + 8.f)) {
      float mn = fmaxf(m, mx);
      float al = exp2_hw(m - mn);
      m = mn;
      l *= al;
      float al0 = __shfl(al, lq * 4 + 0, 64);
      float al1 = __shfl(al, lq * 4 + 1, 64);
      float al2 = __shfl(al, lq * 4 + 2, 64);
      float al3 = __shfl(al, lq * 4 + 3, 64);
#pragma unroll
      for (int oc = 0; oc < 4; ++oc) {
        o[oc][0] *= al0;
        o[oc][1] *= al1;
        o[oc][2] *= al2;
        o[oc][3] *= al3;
      }
    }
    float sum = 0.f;
#pragma unroll
    for (int c = 0; c < 4; ++c) {
#pragma unroll
      for (int r = 0; r < 4; ++r) {
        s[c][r] = exp2_hw(s[c][r] - m);
        sum += s[c][r];
      }
    }
    sum += __shfl_xor(sum, 16, 64);
    sum += __shfl_xor(sum, 32, 64);
    l += sum;
    // P -> wave-private swizzled LDS (packed 8B writes)
#pragma unroll
    for (int c = 0; c < 4; ++c) {
      union { unsigned u[2]; uint2 q2; } pk;
      pk.u[0] = cvtpk(s[c][0], s[c][1]);
      pk.u[1] = cvtpk(s[c][2], s[c][3]);
      *(uint2*)&pw[lr * 64 + ((c * 16 + lq * 4) ^ ((lr & 7) * 8))] = pk.q2;
    }
    bf16x8 pa0 = *(const bf16x8*)&pw[lr * 64 + SWZ8(lr, lq * 8)];
    bf16x8 pa1 = *(const bf16x8*)&pw[lr * 64 + SWZ8(lr, 32 + lq * 8)];
    // O += P V
    __builtin_amdgcn_s_setprio(1);
#pragma unroll
    for (int oc = 0; oc < 4; ++oc) {
      int rv = oc * 16 + lr;
      bf16x8 v0 = *(const bf16x8*)&lsV[cur][rv * 64 + SWZ8(rv, lq * 8)];
      bf16x8 v1 = *(const bf16x8*)&lsV[cur][rv * 64 + SWZ8(rv, 32 + lq * 8)];
      o[oc] = MFMA16(pa0, v0, o[oc]);
      o[oc] = MFMA16(pa1, v1, o[oc]);
    }
    __builtin_amdgcn_s_setprio(0);
    BARRIER();
  }
#undef STAGE
  // redistribute 1/l to output rows (lane q holds l for q = lane&15)
  float inv = 1.0f / l;
  float i0 = __shfl(inv, lq * 4 + 0, 64);
  float i1 = __shfl(inv, lq * 4 + 1, 64);
  float i2 = __shfl(inv, lq * 4 + 2, 64);
  float i3 = __shfl(inv, lq * 4 + 3, 64);
  int b = bh >> 3, h = bh & 7;
#pragma unroll
  for (int oc = 0; oc < 4; ++oc) {
    int q = qf * 64 + wave * 16 + lq * 4;
    int col = h * 64 + oc * 16 + lr;
    ao[((size_t)b * 2048 + q + 0) * 512 + col] = f2bf(o[oc][0] * i0);
    ao[((size_t)b * 2048 + q + 1) * 512 + col] = f2bf(o[oc][1] * i1);
    ao[((size_t)b * 2048 + q + 2) * 512 + col] = f2bf(o[oc][2] * i2);
    ao[((size_t)b * 2048 + q + 3) * 512 + col] = f2bf(o[oc][3] * i3);
  }
}

// ---------------- out GEMM: [8192,512] x [512,512] + bias -> fp32 ----------------
// XCD-partitioned: XCD i owns m-tiles [8i, 8i+8) x all 4 n-tiles.
__global__ __launch_bounds__(256) void gemm_out(
    const u16* __restrict__ A, const u16* __restrict__ BT,
    const float* __restrict__ bias, float* __restrict__ out) {
  __shared__ u16 lsA[128 * 64], lsB[128 * 64];
  int bid = blockIdx.x;
  int xcd = bid & 7, sq = bid >> 3;     // sq 0..31
  int m0 = (xcd * 8 + (sq & 7)) * 128;  // 64 m-tiles
  int n0 = (sq >> 3) * 128;             // 4 n-tiles
  int tid = threadIdx.x;
  int lane = tid & 63, wave = tid >> 6;
  int wm = (wave >> 1) * 64, wn = (wave & 1) * 64;
  int lr = lane & 15, lq = lane >> 4;
  f32x4 acc[4][4] = {};
  for (int kt = 0; kt < 8; ++kt) {
#pragma unroll
    for (int c = 0; c < 4; ++c) {
      int ci = c * 256 + tid;
      int row = ci >> 3, colb = ci & 7;
      int goff = kt * 64 + ((colb * 8) ^ ((row & 7) * 8));
      llds16(&lsA[ci * 8], &A[(size_t)(m0 + row) * 512 + goff]);
      llds16(&lsB[ci * 8], &BT[(size_t)(n0 + row) * 512 + goff]);
    }
    __syncthreads();
#pragma unroll
    for (int ks = 0; ks < 2; ++ks) {
      bf16x8 af[4], bfr[4];
#pragma unroll
      for (int i = 0; i < 4; ++i) {
        int ra = wm + i * 16 + lr;
        af[i] = *(const bf16x8*)&lsA[ra * 64 + SWZ8(ra, ks * 32 + lq * 8)];
        int rb = wn + i * 16 + lr;
        bfr[i] = *(const bf16x8*)&lsB[rb * 64 + SWZ8(rb, ks * 32 + lq * 8)];
      }
#pragma unroll
      for (int i = 0; i < 4; ++i)
#pragma unroll
        for (int j = 0; j < 4; ++j)
          acc[i][j] = MFMA16(af[i], bfr[j], acc[i][j]);
    }
    __syncthreads();
  }
#pragma unroll
  for (int j = 0; j < 4; ++j) {
    int gn = n0 + wn + j * 16 + lr;
    float bj = bias[gn];
#pragma unroll
    for (int i = 0; i < 4; ++i) {
      int gm = m0 + wm + i * 16 + lq * 4;
#pragma unroll
      for (int r = 0; r < 4; ++r)
        out[(size_t)(gm + r) * 512 + gn] = acc[i][j][r] + bj;
    }
  }
}

extern "C" void kernel_launch(void* const* d_in, const int* in_sizes, int n_in,
                              void* d_out, int out_size, void* d_ws, size_t ws_size,
                              hipStream_t stream) {
  const float* x = (const float*)d_in[0];
  const float* ln_g = (const float*)d_in[1];
  const float* ln_b = (const float*)d_in[2];
  const float* w_qkv = (const float*)d_in[3];
  const float* w_out = (const float*)d_in[4];
  const float* b_out = (const float*)d_in[5];
  float* out = (float*)d_out;
  char* ws = (char*)d_ws;

  u16* xn    = (u16*)(ws + 0);          //  8 MB  [8192][512] bf16
  u16* wqkvT = (u16*)(ws + 8388608);    //  1.5 MB [1536][512]
  u16* woutT = (u16*)(ws + 9961472);    //  0.5 MB [512][512]
  u16* qb    = (u16*)(ws + 10485760);   //  8 MB  [B,H,T,D]
  u16* kb    = (u16*)(ws + 18874368);   //  8 MB  [B,H,T,D]
  u16* vtb   = (u16*)(ws + 27262976);   //  8 MB  [B,H,D,T]
  u16* ao    = (u16*)(ws + 35651584);   //  8 MB  [8192][512]

  prep_ln<<<2304, 256, 0, stream>>>(x, ln_g, ln_b, xn, w_qkv, w_out, wqkvT, woutT);
  gemm_qkv<<<768, 256, 0, stream>>>(xn, wqkvT, qb, kb, vtb);
  attn_kernel<<<1024, 256, 0, stream>>>(qb, kb, vtb, ao);
  gemm_out<<<256, 256, 0, stream>>>(ao, woutT, b_out, out);
}

// Round 9
// 151.661 us; speedup vs baseline: 1.1281x; 1.0516x over previous
//
#include <hip/hip_runtime.h>

typedef unsigned short u16;
typedef float f32x4 __attribute__((ext_vector_type(4)));
typedef short bf16x8 __attribute__((ext_vector_type(8)));

#define MFMA16(a, b, c) __builtin_amdgcn_mfma_f32_16x16x32_bf16((a), (b), (c), 0, 0, 0)
// XOR swizzle in 16B (8-short) units within a 64-short row
#define SWZ8(row, off) ((off) ^ (((row) & 7) << 3))

#define CFENCE() asm volatile("" ::: "memory")
#define BARRIER() do { CFENCE(); __builtin_amdgcn_s_barrier(); CFENCE(); } while (0)
#define VMW(n) asm volatile("s_waitcnt vmcnt(" #n ")" ::: "memory")

// round-to-nearest-even f32 -> bf16 (software; proven rounds 0-2)
static __device__ __forceinline__ u16 f2bf(float f) {
  union { float f; unsigned u; } c; c.f = f;
  unsigned r = c.u + 0x7fffu + ((c.u >> 16) & 1u);
  return (u16)(r >> 16);
}

// hardware 2^x (v_exp_f32 IS exp2)
static __device__ __forceinline__ float exp2_hw(float x) {
  float r;
  asm("v_exp_f32 %0, %1" : "=v"(r) : "v"(x));
  return r;
}

// packed f32x2 -> bf16x2 (used ONLY for P, the tolerance-insensitive site)
static __device__ __forceinline__ unsigned cvtpk(float lo, float hi) {
  unsigned r;
  asm("v_cvt_pk_bf16_f32 %0, %1, %2" : "=v"(r) : "v"(lo), "v"(hi));
  return r;
}

static __device__ __forceinline__ void llds16(u16* l, const u16* g) {
  __builtin_amdgcn_global_load_lds((const __attribute__((address_space(1))) void*)g,
                                   (__attribute__((address_space(3))) void*)l, 16, 0, 0);
}

// ---------------- fused prep (weights transpose) + LayerNorm ----------------
// blocks 0..2047: LN wave-per-row. blocks 2048..2303: 64x64 weight tile transpose.
__global__ __launch_bounds__(256) void prep_ln(
    const float* __restrict__ x, const float* __restrict__ g,
    const float* __restrict__ be, u16* __restrict__ xn,
    const float* __restrict__ w_qkv, const float* __restrict__ w_out,
    u16* __restrict__ wqkvT, u16* __restrict__ woutT) {
  __shared__ u16 tile[64][66];
  int bid = blockIdx.x;
  int tid = threadIdx.x;
  if (bid < 2048) {
    int row = bid * 4 + (tid >> 6);
    int lane = tid & 63;
    const float4* xr = (const float4*)(x + (size_t)row * 512) + lane * 2;
    float4 v0 = xr[0], v1 = xr[1];
    float s = v0.x + v0.y + v0.z + v0.w + v1.x + v1.y + v1.z + v1.w;
    float ss = v0.x * v0.x + v0.y * v0.y + v0.z * v0.z + v0.w * v0.w +
               v1.x * v1.x + v1.y * v1.y + v1.z * v1.z + v1.w * v1.w;
#pragma unroll
    for (int msk = 32; msk >= 1; msk >>= 1) {
      s += __shfl_xor(s, msk, 64);
      ss += __shfl_xor(ss, msk, 64);
    }
    float mu = s * (1.f / 512.f);
    float var = ss * (1.f / 512.f) - mu * mu;
    float rs = rsqrtf(var + 1e-5f);
    const float4* gp = (const float4*)g + lane * 2;
    const float4* bp = (const float4*)be + lane * 2;
    float4 g0 = gp[0], g1 = gp[1], b0 = bp[0], b1 = bp[1];
    union { u16 h[8]; uint4 q; } o;
    o.h[0] = f2bf((v0.x - mu) * rs * g0.x + b0.x);
    o.h[1] = f2bf((v0.y - mu) * rs * g0.y + b0.y);
    o.h[2] = f2bf((v0.z - mu) * rs * g0.z + b0.z);
    o.h[3] = f2bf((v0.w - mu) * rs * g0.w + b0.w);
    o.h[4] = f2bf((v1.x - mu) * rs * g1.x + b1.x);
    o.h[5] = f2bf((v1.y - mu) * rs * g1.y + b1.y);
    o.h[6] = f2bf((v1.z - mu) * rs * g1.z + b1.z);
    o.h[7] = f2bf((v1.w - mu) * rs * g1.w + b1.w);
    *(uint4*)&xn[(size_t)row * 512 + lane * 8] = o.q;
    return;
  }
  int pb = bid - 2048;
  const float* src;
  u16* dst;
  int C, tr, tc;
  if (pb < 192) {  // w_qkv [512][1536] -> wqkvT [1536][512]
    src = w_qkv; dst = wqkvT; C = 1536;
    tr = (pb & 7) * 64;
    tc = (pb >> 3) * 64;
  } else {         // w_out [512][512] -> woutT [512][512]
    int b2 = pb - 192;
    src = w_out; dst = woutT; C = 512;
    tr = (b2 & 7) * 64;
    tc = (b2 >> 3) * 64;
  }
  int i = tid >> 4;
  int j4 = (tid & 15) * 4;
#pragma unroll
  for (int p = 0; p < 4; ++p) {
    int row = i + p * 16;
    float4 v = *(const float4*)&src[(size_t)(tr + row) * C + tc + j4];
    tile[row][j4 + 0] = f2bf(v.x);
    tile[row][j4 + 1] = f2bf(v.y);
    tile[row][j4 + 2] = f2bf(v.z);
    tile[row][j4 + 3] = f2bf(v.w);
  }
  __syncthreads();
  int j = tid >> 3;
  int i8 = (tid & 7) * 8;
#pragma unroll
  for (int p = 0; p < 2; ++p) {
    int orow = j + p * 32;
    union { u16 h[8]; uint4 q; } o;
#pragma unroll
    for (int s = 0; s < 8; ++s) o.h[s] = tile[i8 + s][orow];
    *(uint4*)&dst[(size_t)(tc + orow) * 512 + tr + i8] = o.q;
  }
}

// ---------------- QKV GEMM: [8192,512] x [512,1536], scatter q/k/vT ----------------
// BK=32 double-buffered pipeline: stage next K-slab while computing current,
// counted vmcnt(4) so loads stay in flight across barriers (attn-proven).
// Epilogue unchanged: acc -> swizzled LDS tile -> coalesced 16B stores.
__global__ __launch_bounds__(256) void gemm_qkv(
    const u16* __restrict__ A, const u16* __restrict__ BT,
    u16* __restrict__ qb, u16* __restrict__ kb, u16* __restrict__ vtb) {
  __shared__ u16 ls[16384];  // [buf][A 4096 | B 4096] x 2 = 32KB
  int bid = blockIdx.x;
  int xcd = bid & 7, sq = bid >> 3;       // sq 0..95
  int m0 = (xcd * 8 + (sq & 7)) * 128;    // 64 m-tiles
  int n0 = (sq >> 3) * 128;               // 12 n-tiles
  int sec = n0 >> 9;                      // 0=q 1=k 2=v, uniform per block
  int tid = threadIdx.x;
  int lane = tid & 63, wave = tid >> 6;
  int wm = (wave >> 1) * 64, wn = (wave & 1) * 64;
  int lr = lane & 15, lq = lane >> 4;
  // staging: A tile [128][32] = 512 x 16B units; thread covers units tid, tid+256
  int ar0 = tid >> 2, ac0 = tid & 3;  // rows 0..63   (row&3 == (row+64)&3)
  const u16* Ar0 = &A[(size_t)(m0 + ar0) * 512 + ((ac0 ^ (ar0 & 3)) * 8)];
  const u16* Ar1 = &A[(size_t)(m0 + 64 + ar0) * 512 + ((ac0 ^ (ar0 & 3)) * 8)];
  const u16* Br0 = &BT[(size_t)(n0 + ar0) * 512 + ((ac0 ^ (ar0 & 3)) * 8)];
  const u16* Br1 = &BT[(size_t)(n0 + 64 + ar0) * 512 + ((ac0 ^ (ar0 & 3)) * 8)];

#define STAGEG(b, kt_)                                 \
  do {                                                 \
    u16* la = ls + (b) * 8192;                         \
    u16* lb = la + 4096;                               \
    int gc = (kt_) * 32;                               \
    llds16(&la[tid * 8], Ar0 + gc);                    \
    llds16(&la[(tid + 256) * 8], Ar1 + gc);            \
    llds16(&lb[tid * 8], Br0 + gc);                    \
    llds16(&lb[(tid + 256) * 8], Br1 + gc);            \
  } while (0)

  f32x4 acc[4][4] = {};
  STAGEG(0, 0);
  for (int kt = 0; kt < 16; ++kt) {
    int cur = kt & 1;
    if (kt < 15) {
      STAGEG(cur ^ 1, kt + 1);
      VMW(4);
    } else {
      VMW(0);
    }
    BARRIER();
    u16* la = ls + cur * 8192;
    u16* lb = la + 4096;
    bf16x8 af[4], bfr[4];
#pragma unroll
    for (int i = 0; i < 4; ++i) {
      int ra = wm + i * 16 + lr;
      af[i] = *(const bf16x8*)&la[ra * 32 + ((lq ^ (ra & 3)) * 8)];
      int rb = wn + i * 16 + lr;
      bfr[i] = *(const bf16x8*)&lb[rb * 32 + ((lq ^ (rb & 3)) * 8)];
    }
    __builtin_amdgcn_s_setprio(1);
#pragma unroll
    for (int i = 0; i < 4; ++i)
#pragma unroll
      for (int j = 0; j < 4; ++j)
        acc[i][j] = MFMA16(af[i], bfr[j], acc[i][j]);
    __builtin_amdgcn_s_setprio(0);
    BARRIER();
  }
#undef STAGEG
  // ---- epilogue: acc -> LDS (swizzled u16) -> coalesced 16B stores ----
  int b = m0 >> 11, t0 = m0 & 2047;
  float sc = (sec == 0) ? 0.180336880f : 1.0f;
  if (sec < 2) {
#pragma unroll
    for (int i = 0; i < 4; ++i)
#pragma unroll
      for (int j = 0; j < 4; ++j) {
        int col = wn + j * 16 + lr;
#pragma unroll
        for (int r = 0; r < 4; ++r) {
          int row = wm + i * 16 + lq * 4 + r;
          ls[row * 128 + (col ^ ((row & 7) << 3))] = f2bf(acc[i][j][r] * sc);
        }
      }
    __syncthreads();
    u16* dst = (sec == 0) ? qb : kb;
#pragma unroll
    for (int s = 0; s < 8; ++s) {
      int li = s * 256 + tid;
      int row = li >> 4, c8 = (li & 15) * 8;
      uint4 v = *(uint4*)&ls[row * 128 + (c8 ^ ((row & 7) << 3))];
      int gn = n0 + c8;
      int h = (gn >> 6) & 7, d = gn & 63;
      *(uint4*)&dst[((size_t)(b * 8 + h) * 2048 + t0 + row) * 64 + d] = v;
    }
  } else {
#pragma unroll
    for (int i = 0; i < 4; ++i)
#pragma unroll
      for (int j = 0; j < 4; ++j) {
        int col = wn + j * 16 + lr;
#pragma unroll
        for (int r = 0; r < 4; ++r) {
          int row = wm + i * 16 + lq * 4 + r;
          ls[col * 128 + (row ^ ((col & 7) << 3))] = f2bf(acc[i][j][r]);
        }
      }
    __syncthreads();
#pragma unroll
    for (int s = 0; s < 8; ++s) {
      int li = s * 256 + tid;
      int dcol = li >> 4, t8 = (li & 15) * 8;
      uint4 v = *(uint4*)&ls[dcol * 128 + (t8 ^ ((dcol & 7) << 3))];
      int gn = n0 + dcol;
      int h = (gn >> 6) & 7, d = gn & 63;
      *(uint4*)&vtb[((size_t)(b * 8 + h) * 64 + d) * 2048 + t0 + t8] = v;
    }
  }
}

// ---------------- frame-causal flash attention (R5 structure + defer-max) ----------------
__global__ __launch_bounds__(256) void attn_kernel(
    const u16* __restrict__ qb, const u16* __restrict__ kb,
    const u16* __restrict__ vtb, u16* __restrict__ ao) {
  int blk = blockIdx.x;
  int xcd = blk & 7;
  int seq = blk >> 3;            // 0..127
  int bh = xcd * 4 + (seq & 3);  // 4 bh per XCD -> L2-resident K/V
  int qf = 31 - (seq >> 2);      // heavy frames first
  int tid = threadIdx.x, lane = tid & 63, wave = tid >> 6;
  int lr = lane & 15, lq = lane >> 4;
  __shared__ u16 lsK[2][64 * 64], lsV[2][64 * 64];
  __shared__ u16 lsP[4][16 * 64];
  const u16* kfb = kb + (size_t)bh * 2048 * 64;
  const u16* vfb = vtb + (size_t)bh * 64 * 2048;

  int ci0 = tid, ci1 = 256 + tid;
  int r0 = ci0 >> 3, cb0 = ci0 & 7, sw0 = (cb0 * 8) ^ ((r0 & 7) * 8);
  int r1 = ci1 >> 3, cb1 = ci1 & 7, sw1 = (cb1 * 8) ^ ((r1 & 7) * 8);

#define STAGE(buf, kf_)                                                        \
  do {                                                                         \
    const u16* kp = kfb + (size_t)(kf_) * 64 * 64;                             \
    llds16(&lsK[buf][ci0 * 8], &kp[(size_t)r0 * 64 + sw0]);                    \
    llds16(&lsK[buf][ci1 * 8], &kp[(size_t)r1 * 64 + sw1]);                    \
    llds16(&lsV[buf][ci0 * 8], &vfb[(size_t)r0 * 2048 + (kf_) * 64 + sw0]);    \
    llds16(&lsV[buf][ci1 * 8], &vfb[(size_t)r1 * 2048 + (kf_) * 64 + sw1]);    \
  } while (0)

  STAGE(0, 0);

  const u16* qbase = qb + ((size_t)bh * 2048 + qf * 64) * 64;
  int qrow = wave * 16 + lr;
  bf16x8 qa0 = *(const bf16x8*)&qbase[qrow * 64 + lq * 8];
  bf16x8 qa1 = *(const bf16x8*)&qbase[qrow * 64 + 32 + lq * 8];

  f32x4 o[4] = {};
  float m = -1e30f, l = 0.f;
  u16* pw = lsP[wave];

  for (int kf = 0; kf <= qf; ++kf) {
    int cur = kf & 1;
    if (kf < qf) {
      STAGE(cur ^ 1, kf + 1);
      VMW(4);
    } else {
      VMW(0);
    }
    BARRIER();
    f32x4 s[4];
    __builtin_amdgcn_s_setprio(1);
#pragma unroll
    for (int c = 0; c < 4; ++c) {
      int rk = c * 16 + lr;
      bf16x8 k0 = *(const bf16x8*)&lsK[cur][rk * 64 + SWZ8(rk, lq * 8)];
      bf16x8 k1 = *(const bf16x8*)&lsK[cur][rk * 64 + SWZ8(rk, 32 + lq * 8)];
      f32x4 z = {};
      z = MFMA16(k0, qa0, z);
      z = MFMA16(k1, qa1, z);
      s[c] = z;
    }
    __builtin_amdgcn_s_setprio(0);
    float m0 = fmaxf(fmaxf(s[0][0], s[0][1]), fmaxf(s[0][2], s[0][3]));
    float m1 = fmaxf(fmaxf(s[1][0], s[1][1]), fmaxf(s[1][2], s[1][3]));
    float m2 = fmaxf(fmaxf(s[2][0], s[2][1]), fmaxf(s[2][2], s[2][3]));
    float m3 = fmaxf(fmaxf(s[3][0], s[3][1]), fmaxf(s[3][2], s[3][3]));
    float mx = fmaxf(fmaxf(m0, m1), fmaxf(m2, m3));
    mx = fmaxf(mx, __shfl_xor(mx, 16, 64));
    mx = fmaxf(mx, __shfl_xor(mx, 32, 64));
    if (!__all(mx <= m + 8.f)) {
      float mn = fmaxf(m, mx);
      float al = exp2_hw(m - mn);
      m = mn;
      l *= al;
      float al0 = __shfl(al, lq * 4 + 0, 64);
      float al1 = __shfl(al, lq * 4 + 1, 64);
      float al2 = __shfl(al, lq * 4 + 2, 64);
      float al3 = __shfl(al, lq * 4 + 3, 64);
#pragma unroll
      for (int oc = 0; oc < 4; ++oc) {
        o[oc][0] *= al0;
        o[oc][1] *= al1;
        o[oc][2] *= al2;
        o[oc][3] *= al3;
      }
    }
    float sum = 0.f;
#pragma unroll
    for (int c = 0; c < 4; ++c) {
#pragma unroll
      for (int r = 0; r < 4; ++r) {
        s[c][r] = exp2_hw(s[c][r] - m);
        sum += s[c][r];
      }
    }
    sum += __shfl_xor(sum, 16, 64);
    sum += __shfl_xor(sum, 32, 64);
    l += sum;
#pragma unroll
    for (int c = 0; c < 4; ++c) {
      union { unsigned u[2]; uint2 q2; } pk;
      pk.u[0] = cvtpk(s[c][0], s[c][1]);
      pk.u[1] = cvtpk(s[c][2], s[c][3]);
      *(uint2*)&pw[lr * 64 + ((c * 16 + lq * 4) ^ ((lr & 7) * 8))] = pk.q2;
    }
    bf16x8 pa0 = *(const bf16x8*)&pw[lr * 64 + SWZ8(lr, lq * 8)];
    bf16x8 pa1 = *(const bf16x8*)&pw[lr * 64 + SWZ8(lr, 32 + lq * 8)];
    __builtin_amdgcn_s_setprio(1);
#pragma unroll
    for (int oc = 0; oc < 4; ++oc) {
      int rv = oc * 16 + lr;
      bf16x8 v0 = *(const bf16x8*)&lsV[cur][rv * 64 + SWZ8(rv, lq * 8)];
      bf16x8 v1 = *(const bf16x8*)&lsV[cur][rv * 64 + SWZ8(rv, 32 + lq * 8)];
      o[oc] = MFMA16(pa0, v0, o[oc]);
      o[oc] = MFMA16(pa1, v1, o[oc]);
    }
    __builtin_amdgcn_s_setprio(0);
    BARRIER();
  }
#undef STAGE
  float inv = 1.0f / l;
  float i0 = __shfl(inv, lq * 4 + 0, 64);
  float i1 = __shfl(inv, lq * 4 + 1, 64);
  float i2 = __shfl(inv, lq * 4 + 2, 64);
  float i3 = __shfl(inv, lq * 4 + 3, 64);
  int b = bh >> 3, h = bh & 7;
#pragma unroll
  for (int oc = 0; oc < 4; ++oc) {
    int q = qf * 64 + wave * 16 + lq * 4;
    int col = h * 64 + oc * 16 + lr;
    ao[((size_t)b * 2048 + q + 0) * 512 + col] = f2bf(o[oc][0] * i0);
    ao[((size_t)b * 2048 + q + 1) * 512 + col] = f2bf(o[oc][1] * i1);
    ao[((size_t)b * 2048 + q + 2) * 512 + col] = f2bf(o[oc][2] * i2);
    ao[((size_t)b * 2048 + q + 3) * 512 + col] = f2bf(o[oc][3] * i3);
  }
}

// ---------------- out GEMM: [8192,512] x [512,512] + bias -> fp32 ----------------
// Same BK=32 double-buffered pipeline as gemm_qkv.
__global__ __launch_bounds__(256) void gemm_out(
    const u16* __restrict__ A, const u16* __restrict__ BT,
    const float* __restrict__ bias, float* __restrict__ out) {
  __shared__ u16 ls[16384];
  int bid = blockIdx.x;
  int xcd = bid & 7, sq = bid >> 3;     // sq 0..31
  int m0 = (xcd * 8 + (sq & 7)) * 128;  // 64 m-tiles
  int n0 = (sq >> 3) * 128;             // 4 n-tiles
  int tid = threadIdx.x;
  int lane = tid & 63, wave = tid >> 6;
  int wm = (wave >> 1) * 64, wn = (wave & 1) * 64;
  int lr = lane & 15, lq = lane >> 4;
  int ar0 = tid >> 2, ac0 = tid & 3;
  const u16* Ar0 = &A[(size_t)(m0 + ar0) * 512 + ((ac0 ^ (ar0 & 3)) * 8)];
  const u16* Ar1 = &A[(size_t)(m0 + 64 + ar0) * 512 + ((ac0 ^ (ar0 & 3)) * 8)];
  const u16* Br0 = &BT[(size_t)(n0 + ar0) * 512 + ((ac0 ^ (ar0 & 3)) * 8)];
  const u16* Br1 = &BT[(size_t)(n0 + 64 + ar0) * 512 + ((ac0 ^ (ar0 & 3)) * 8)];

#define STAGEG(b, kt_)                                 \
  do {                                                 \
    u16* la = ls + (b) * 8192;                         \
    u16* lb = la + 4096;                               \
    int gc = (kt_) * 32;                               \
    llds16(&la[tid * 8], Ar0 + gc);                    \
    llds16(&la[(tid + 256) * 8], Ar1 + gc);            \
    llds16(&lb[tid * 8], Br0 + gc);                    \
    llds16(&lb[(tid + 256) * 8], Br1 + gc);            \
  } while (0)

  f32x4 acc[4][4] = {};
  STAGEG(0, 0);
  for (int kt = 0; kt < 16; ++kt) {
    int cur = kt & 1;
    if (kt < 15) {
      STAGEG(cur ^ 1, kt + 1);
      VMW(4);
    } else {
      VMW(0);
    }
    BARRIER();
    u16* la = ls + cur * 8192;
    u16* lb = la + 4096;
    bf16x8 af[4], bfr[4];
#pragma unroll
    for (int i = 0; i < 4; ++i) {
      int ra = wm + i * 16 + lr;
      af[i] = *(const bf16x8*)&la[ra * 32 + ((lq ^ (ra & 3)) * 8)];
      int rb = wn + i * 16 + lr;
      bfr[i] = *(const bf16x8*)&lb[rb * 32 + ((lq ^ (rb & 3)) * 8)];
    }
    __builtin_amdgcn_s_setprio(1);
#pragma unroll
    for (int i = 0; i < 4; ++i)
#pragma unroll
      for (int j = 0; j < 4; ++j)
        acc[i][j] = MFMA16(af[i], bfr[j], acc[i][j]);
    __builtin_amdgcn_s_setprio(0);
    BARRIER();
  }
#undef STAGEG
#pragma unroll
  for (int j = 0; j < 4; ++j) {
    int gn = n0 + wn + j * 16 + lr;
    float bj = bias[gn];
#pragma unroll
    for (int i = 0; i < 4; ++i) {
      int gm = m0 + wm + i * 16 + lq * 4;
#pragma unroll
      for (int r = 0; r < 4; ++r)
        out[(size_t)(gm + r) * 512 + gn] = acc[i][j][r] + bj;
    }
  }
}

extern "C" void kernel_launch(void* const* d_in, const int* in_sizes, int n_in,
                              void* d_out, int out_size, void* d_ws, size_t ws_size,
                              hipStream_t stream) {
  const float* x = (const float*)d_in[0];
  const float* ln_g = (const float*)d_in[1];
  const float* ln_b = (const float*)d_in[2];
  const float* w_qkv = (const float*)d_in[3];
  const float* w_out = (const float*)d_in[4];
  const float* b_out = (const float*)d_in[5];
  float* out = (float*)d_out;
  char* ws = (char*)d_ws;

  u16* xn    = (u16*)(ws + 0);          //  8 MB  [8192][512] bf16
  u16* wqkvT = (u16*)(ws + 8388608);    //  1.5 MB [1536][512]
  u16* woutT = (u16*)(ws + 9961472);    //  0.5 MB [512][512]
  u16* qb    = (u16*)(ws + 10485760);   //  8 MB  [B,H,T,D]
  u16* kb    = (u16*)(ws + 18874368);   //  8 MB  [B,H,T,D]
  u16* vtb   = (u16*)(ws + 27262976);   //  8 MB  [B,H,D,T]
  u16* ao    = (u16*)(ws + 35651584);   //  8 MB  [8192][512]

  prep_ln<<<2304, 256, 0, stream>>>(x, ln_g, ln_b, xn, w_qkv, w_out, wqkvT, woutT);
  gemm_qkv<<<768, 256, 0, stream>>>(xn, wqkvT, qb, kb, vtb);
  attn_kernel<<<1024, 256, 0, stream>>>(qb, kb, vtb, ao);
  gemm_out<<<256, 256, 0, stream>>>(ao, woutT, b_out, out);
}